// Round 12
// baseline (255.998 us; speedup 1.0000x reference)
//
#include <hip/hip_runtime.h>
#include <math.h>

// Problem constants (match reference)
#define B_TOK 16384
#define H_DIM 2048
#define NE    8
#define TOPK  2
#define HFD   512

#define BK 32
#define NKSTEP (H_DIM / BK)   // 64
#define PTMAX 129             // covers worst-case expert count
#define PROWS 33792           // padded P rows total (8 experts, 128-padded)

// Workspace layout (bytes)
static constexpr size_t OFF_COUNTS = 0;           // 32 B
static constexpr size_t OFF_CBASE  = 128;         // cbase[8] + cpad[8]
static constexpr size_t OFF_BUCKET = 1024;        // 512 KB
static constexpr size_t OFF_WSLOT  = 525312;      // 128 KB
static constexpr size_t OFF_ROUTE  = 656384;      // 64 KB
static constexpr size_t OFF_INV    = 721920;      // 128 KB -> 849920
static constexpr size_t OFF_WGT    = 1u << 20;    // 8 replicas x 64 KB = 512 KB
static constexpr size_t OFF_P4     = 1572864;     // 4 x 33792 floats = 528 KB
static constexpr size_t OFF_W1Q    = 4u << 20;    // 16 MB -> ends 20 MB
static constexpr size_t OFF_XB     = 20971520;    // 64 MB bf16 x -> ends 84 MB

typedef short bfrag __attribute__((ext_vector_type(8)));   // 8 bf16 (4 VGPR)
typedef float facc  __attribute__((ext_vector_type(16)));  // 32x32 accum

__device__ inline unsigned short f2bf(float f) {
    union { float f; unsigned u; } v; v.f = f;
    unsigned r = v.u + 0x7FFFu + ((v.u >> 16) & 1u);
    return (unsigned short)(r >> 16);
}
__device__ inline unsigned pack2(float lo, float hi) {
    return (unsigned)f2bf(lo) | ((unsigned)f2bf(hi) << 16);
}

__device__ __forceinline__ void gload_lds16(const void* g, void* l) {
    __builtin_amdgcn_global_load_lds(
        (const __attribute__((address_space(1))) unsigned int*)g,
        (__attribute__((address_space(3))) unsigned int*)l, 16, 0, 0);
}

// ---------------------------------------------------------------------------
// Transpose gate weights: Wg [H][E] -> 8 replicas of WgT [E][H].
// ---------------------------------------------------------------------------
__global__ __launch_bounds__(256)
void wg_transpose_kernel(const float* __restrict__ Wg,
                         float* __restrict__ WgT)
{
    const int t = threadIdx.x;
    #pragma unroll
    for (int rep = 0; rep < H_DIM / 256; ++rep) {
        const int h = rep * 256 + t;
        const float4 a = *reinterpret_cast<const float4*>(Wg + (size_t)h * NE);
        const float4 b = *reinterpret_cast<const float4*>(Wg + (size_t)h * NE + 4);
        #pragma unroll
        for (int rr = 0; rr < 8; ++rr) {
            float* W = WgT + (size_t)rr * (NE * H_DIM);
            W[0 * H_DIM + h] = a.x;  W[1 * H_DIM + h] = a.y;
            W[2 * H_DIM + h] = a.z;  W[3 * H_DIM + h] = a.w;
            W[4 * H_DIM + h] = b.x;  W[5 * H_DIM + h] = b.y;
            W[6 * H_DIM + h] = b.z;  W[7 * H_DIM + h] = b.w;
        }
    }
}

// ---------------------------------------------------------------------------
// Prep W1: [E][H][HF] fp32 -> per-(e, f-quarter) k-slot-major bf16 images:
//   W1q[(e*4+fq)*64 + kstep][slot(4)][fl(128)][j(8)]  (8 KB per image)
// element k = kstep*32 + slot*8 + j, f = fq*128 + fl. Each image is exactly
// one expert-kernel A-stage (linear copy, conflict-free k-slot-major reads).
// ---------------------------------------------------------------------------
__global__ __launch_bounds__(256)
void prep_w1_kernel(const float* __restrict__ W1,
                    unsigned short* __restrict__ W1q)
{
    const int e     = blockIdx.x >> 6;
    const int kstep = blockIdx.x & 63;
    const int tid   = threadIdx.x;

    const float* src = W1 + ((size_t)e * H_DIM + kstep * BK) * HFD;

    #pragma unroll
    for (int slot = 0; slot < 4; ++slot) {
        #pragma unroll
        for (int half = 0; half < 2; ++half) {
            const int f  = half * 256 + tid;
            const int fq = f >> 7;
            const int fl = f & 127;
            float v[8];
            #pragma unroll
            for (int j = 0; j < 8; ++j)
                v[j] = src[(size_t)(slot * 8 + j) * HFD + f];   // lane-coalesced
            uint4 p;
            p.x = pack2(v[0], v[1]); p.y = pack2(v[2], v[3]);
            p.z = pack2(v[4], v[5]); p.w = pack2(v[6], v[7]);
            *reinterpret_cast<uint4*>(
                W1q + ((size_t)((e * 4 + fq) * 64 + kstep)) * 4096
                    + (slot * 128 + fl) * 8) = p;
        }
    }
}

// ---------------------------------------------------------------------------
// Gate logits: 256 blocks x 64 tokens; WgT staged once into LDS.
// Also converts x rows to bf16 (xb), which the expert kernel gathers.
// ---------------------------------------------------------------------------
__global__ __launch_bounds__(256)
void gate_logits_kernel(const float* __restrict__ x,
                        const float* __restrict__ WgT,
                        const float* __restrict__ bg,
                        float* __restrict__ out_logits,
                        float* __restrict__ wslot,
                        int*   __restrict__ route,
                        unsigned short* __restrict__ xb)
{
    __shared__ float Wlds[NE * H_DIM];   // 64 KB

    const int tid = threadIdx.x;
    const float* Wsrc = WgT + (size_t)(blockIdx.x & 7) * (NE * H_DIM);
    #pragma unroll
    for (int i = 0; i < (NE * H_DIM) / (256 * 4); ++i) {
        const int idx = (i * 256 + tid) * 4;
        *reinterpret_cast<float4*>(&Wlds[idx]) =
            *reinterpret_cast<const float4*>(Wsrc + idx);
    }
    __syncthreads();

    const int w = tid >> 6, l = tid & 63;
    const int tbase = blockIdx.x * 64 + w * 16;

    for (int pass = 0; pass < 4; ++pass) {
        const int t0 = tbase + pass * 4;
        float acc[4][NE];
        #pragma unroll
        for (int j = 0; j < 4; ++j)
            #pragma unroll
            for (int e = 0; e < NE; ++e) acc[j][e] = 0.f;

        for (int i = 0; i < 8; ++i) {
            const int h = i * 256 + 4 * l;
            float4 xv[4];
            #pragma unroll
            for (int j = 0; j < 4; ++j)
                xv[j] = *reinterpret_cast<const float4*>(
                    x + (size_t)(t0 + j) * H_DIM + h);
            #pragma unroll
            for (int j = 0; j < 4; ++j) {
                uint2 pk;
                pk.x = pack2(xv[j].x, xv[j].y);
                pk.y = pack2(xv[j].z, xv[j].w);
                *reinterpret_cast<uint2*>(xb + (size_t)(t0 + j) * H_DIM + h) = pk;
            }
            #pragma unroll
            for (int e = 0; e < NE; ++e) {
                const float4 wv = *reinterpret_cast<const float4*>(&Wlds[e * H_DIM + h]);
                #pragma unroll
                for (int j = 0; j < 4; ++j)
                    acc[j][e] += xv[j].x * wv.x + xv[j].y * wv.y
                               + xv[j].z * wv.z + xv[j].w * wv.w;
            }
        }

        #pragma unroll
        for (int j = 0; j < 4; ++j)
            #pragma unroll
            for (int e = 0; e < NE; ++e)
                #pragma unroll
                for (int off = 32; off > 0; off >>= 1)
                    acc[j][e] += __shfl_xor(acc[j][e], off, 64);

        if (l == 0) {
            #pragma unroll
            for (int j = 0; j < 4; ++j) {
                const int tok = t0 + j;
                float lg[NE];
                #pragma unroll
                for (int e = 0; e < NE; ++e) lg[e] = acc[j][e] + bg[e];

                float4* lo = reinterpret_cast<float4*>(out_logits + (size_t)tok * NE);
                lo[0] = make_float4(lg[0], lg[1], lg[2], lg[3]);
                lo[1] = make_float4(lg[4], lg[5], lg[6], lg[7]);

                int i0 = 0; float v0 = lg[0];
                #pragma unroll
                for (int e = 1; e < NE; ++e)
                    if (lg[e] > v0) { v0 = lg[e]; i0 = e; }
                int i1 = -1; float v1 = -3.4e38f;
                #pragma unroll
                for (int e = 0; e < NE; ++e)
                    if (e != i0 && lg[e] > v1) { v1 = lg[e]; i1 = e; }

                const float w0 = 1.f / (1.f + expf(v1 - v0));
                wslot[tok * 2]     = w0;
                wslot[tok * 2 + 1] = 1.f - w0;
                route[tok] = i0 | (i1 << 8);
            }
        }
    }
}

// ---------------------------------------------------------------------------
// Route/bucket: LDS-aggregated histogram; 8 global atomics per block.
// ---------------------------------------------------------------------------
__global__ __launch_bounds__(1024)
void route_kernel(const int* __restrict__ route,
                  int* __restrict__ counts,
                  int* __restrict__ bucket)
{
    __shared__ int lcnt[NE];
    __shared__ int lbase[NE];
    const int tid = threadIdx.x;
    const int tok = blockIdx.x * 1024 + tid;

    if (tid < NE) lcnt[tid] = 0;
    __syncthreads();

    const int rt = route[tok];
    const int i0 = rt & 255;
    const int i1 = rt >> 8;
    const int r0 = atomicAdd(&lcnt[i0], 1);
    const int r1 = atomicAdd(&lcnt[i1], 1);
    __syncthreads();

    if (tid < NE) lbase[tid] = atomicAdd(&counts[tid], lcnt[tid]);
    __syncthreads();

    bucket[i0 * B_TOK + lbase[i0] + r0] = tok * 2;
    bucket[i1 * B_TOK + lbase[i1] + r1] = tok * 2 + 1;
}

// ---------------------------------------------------------------------------
// Prefix: cbase[e] = row base; cpad[e] = count padded to 128.
// ---------------------------------------------------------------------------
__global__ void prefix_kernel(const int* __restrict__ counts,
                              int* __restrict__ cbase)
{
    if (threadIdx.x == 0 && blockIdx.x == 0) {
        int acc = 0;
        for (int e = 0; e < NE; ++e) {
            const int cp = ((counts[e] + 127) >> 7) << 7;
            cbase[e]      = acc;
            cbase[NE + e] = cp;
            acc += cp;
        }
    }
}

// ---------------------------------------------------------------------------
// invfill: inv[entry] = global P row for each bucket slot.
// ---------------------------------------------------------------------------
__global__ __launch_bounds__(256)
void invfill_kernel(const int* __restrict__ bucket,
                    const int* __restrict__ counts,
                    const int* __restrict__ cbase,
                    int* __restrict__ inv)
{
    const int e   = blockIdx.x & 7;
    const int pos = (blockIdx.x >> 3) * 256 + threadIdx.x;
    if (pos < counts[e]) inv[bucket[e * B_TOK + pos]] = cbase[e] + pos;
}

// ---------------------------------------------------------------------------
// Expert MFMA (m97 + T3/T4): block = (e, f-quarter fq, 128-pos tile).
// 256 thr / 4 waves (2m x 2n), tile 128 f x 128 pos, BK=32, DOUBLE-buffered
// 33 KB LDS -> 4 blocks/CU co-resident. Per step: STAGE(kk+1, other buf)
// [uniform 4 gload_lds16/thread: 2 A linear + 2 B full-line gather] ->
// s_waitcnt vmcnt(4) (counted -- never drains next tile's loads) ->
// barrier -> 8 ds_read_b128 + 8 MFMA/wave -> barrier.
// B chunk swizzle c' = slot ^ ((row>>1)&3): 8-row full bank sweep on read.
// Deterministic single-writer P4[fq] partials, fixed-order combine.
// ---------------------------------------------------------------------------
__global__ __launch_bounds__(256, 4)
void expert_mfma_kernel(const unsigned short* __restrict__ xb,
                        const unsigned short* __restrict__ W1q,
                        const float* __restrict__ b1,
                        const float* __restrict__ W2,
                        const int* __restrict__ counts,
                        const int* __restrict__ cbase,
                        const int* __restrict__ bucket,
                        float* __restrict__ P4)
{
    const int e  = blockIdx.x & 7;
    const int r  = blockIdx.x >> 3;
    const int fq = r & 3;
    const int pt = r >> 2;
    const int n  = counts[e];
    const int pos0 = pt * 128;
    if (pos0 >= n) return;
    const int nt = min(128, n - pos0);
    const int cb = cbase[e];

    __shared__ unsigned short Abuf[2][4096];   // [slot4][fl128][j8]  8 KB each
    __shared__ unsigned short Bbuf[2][4096];   // [row128][c'4][j8]   8 KB each
    __shared__ float o_part[2][128];           // 1 KB

    const int tid = threadIdx.x;
    const int w   = tid >> 6;
    const int l   = tid & 63;
    const int lo5 = l & 31;
    const int hi  = l >> 5;
    const int wm  = w & 1;      // m half (64 f rows)
    const int wn  = w >> 1;     // n half (64 pos cols)

    const unsigned short* Aimg = W1q + (size_t)((e * 4 + fq) * 64) * 4096;

    // B gather: entry u -> (row = u>>2, c' = u&3); source chunk pre-XORed
    // (c' ^ ((row>>1)&3)) so read-side XOR retrieves the right k-chunk.
    const int u0 = tid, u1 = 256 + tid;
    const int r0 = u0 >> 2, r1 = u1 >> 2;
    const int t0 = bucket[e * B_TOK + min(pos0 + r0, n - 1)] >> 1;
    const int t1 = bucket[e * B_TOK + min(pos0 + r1, n - 1)] >> 1;
    const unsigned short* xsrc0 =
        xb + (size_t)t0 * H_DIM + (((u0 & 3) ^ ((r0 >> 1) & 3)) * 8);
    const unsigned short* xsrc1 =
        xb + (size_t)t1 * H_DIM + (((u1 & 3) ^ ((r1 >> 1) & 3)) * 8);
    const int o0 = u0 * 8;   // linear LDS dest (shorts)
    const int o1 = u1 * 8;

    facc acc00, acc01, acc10, acc11;
    #pragma unroll
    for (int q = 0; q < 16; ++q) {
        acc00[q] = 0.f; acc01[q] = 0.f; acc10[q] = 0.f; acc11[q] = 0.f;
    }

    // Uniform 4 loads per thread per step (vmcnt counting depends on it).
    #define STAGE(KK, BUF) do {                                                \
        const unsigned short* as_ = Aimg + (size_t)(KK) * 4096;                \
        gload_lds16(as_ + o0, &Abuf[BUF][o0]);                                 \
        gload_lds16(as_ + o1, &Abuf[BUF][o1]);                                 \
        gload_lds16(xsrc0 + (KK) * BK, &Bbuf[BUF][o0]);                        \
        gload_lds16(xsrc1 + (KK) * BK, &Bbuf[BUF][o1]);                        \
    } while (0)

    STAGE(0, 0);

    for (int kk = 0; kk < NKSTEP; ++kk) {
        const int cur = kk & 1;
        if (kk < NKSTEP - 1) {
            STAGE(kk + 1, cur ^ 1);
            asm volatile("s_waitcnt vmcnt(4)" ::: "memory");  // step kk landed
        } else {
            asm volatile("s_waitcnt vmcnt(0)" ::: "memory");
        }
        __builtin_amdgcn_s_barrier();   // buf[cur] visible to all waves

        #pragma unroll
        for (int s = 0; s < 2; ++s) {
            const int slot = s * 2 + hi;
            const int row0 = wn * 64 + lo5;
            const int row1 = row0 + 32;
            const int c0 = slot ^ ((row0 >> 1) & 3);
            const int c1 = slot ^ ((row1 >> 1) & 3);
            const bfrag a0 = *reinterpret_cast<const bfrag*>(
                &Abuf[cur][(slot * 128 + wm * 64 + lo5) * 8]);
            const bfrag a1 = *reinterpret_cast<const bfrag*>(
                &Abuf[cur][(slot * 128 + wm * 64 + 32 + lo5) * 8]);
            const bfrag b0 = *reinterpret_cast<const bfrag*>(
                &Bbuf[cur][(row0 * 4 + c0) * 8]);
            const bfrag b1v = *reinterpret_cast<const bfrag*>(
                &Bbuf[cur][(row1 * 4 + c1) * 8]);
            acc00 = __builtin_amdgcn_mfma_f32_32x32x16_bf16(a0, b0,  acc00, 0, 0, 0);
            acc01 = __builtin_amdgcn_mfma_f32_32x32x16_bf16(a0, b1v, acc01, 0, 0, 0);
            acc10 = __builtin_amdgcn_mfma_f32_32x32x16_bf16(a1, b0,  acc10, 0, 0, 0);
            acc11 = __builtin_amdgcn_mfma_f32_32x32x16_bf16(a1, b1v, acc11, 0, 0, 0);
        }
        __builtin_amdgcn_s_barrier();   // reads retired before buf reuse
    }
    #undef STAGE

    // Epilogue: bias + exact GELU + W2 dot; reduce over this block's 128 f.
    const float* b1e = b1 + e * HFD + fq * 128;
    const float* W2e = W2 + e * HFD + fq * 128;
    const float kInvSqrt2 = 0.70710678118654752f;

    float po0 = 0.f, po1 = 0.f;
    #pragma unroll
    for (int mb = 0; mb < 2; ++mb) {
        const int base = wm * 64 + mb * 32 + 4 * hi;
        #pragma unroll
        for (int q = 0; q < 16; ++q) {
            const int frow = base + (q & 3) + 8 * (q >> 2);
            const float bv = b1e[frow];
            const float wv = W2e[frow];
            const float h0 = (mb ? acc10[q] : acc00[q]) + bv;
            const float h1 = (mb ? acc11[q] : acc01[q]) + bv;
            po0 += 0.5f * h0 * (1.f + erff(h0 * kInvSqrt2)) * wv;
            po1 += 0.5f * h1 * (1.f + erff(h1 * kInvSqrt2)) * wv;
        }
    }
    po0 += __shfl_xor(po0, 32, 64);
    po1 += __shfl_xor(po1, 32, 64);

    if (hi == 0) {
        o_part[wm][wn * 64 + lo5]      = po0;
        o_part[wm][wn * 64 + 32 + lo5] = po1;
    }
    __syncthreads();

    if (tid < nt)
        P4[(size_t)fq * PROWS + cb + pos0 + tid] =
            o_part[0][tid] + o_part[1][tid];
}

// ---------------------------------------------------------------------------
// Combine: out[t] = w0*Σ_fq P4[fq][g0] + w1*Σ_fq P4[fq][g1].
// Fixed summation order -> deterministic, no atomics anywhere.
// ---------------------------------------------------------------------------
__global__ __launch_bounds__(256)
void combine_kernel(const int* __restrict__ inv,
                    const float* __restrict__ P4,
                    const float* __restrict__ wslot,
                    float* __restrict__ out_scores)
{
    const int t = blockIdx.x * 256 + threadIdx.x;
    if (t >= B_TOK) return;
    const int g0 = inv[2 * t];
    const int g1 = inv[2 * t + 1];
    const float s0 = ((P4[g0] + P4[PROWS + g0]) + P4[2 * PROWS + g0])
                   + P4[3 * PROWS + g0];
    const float s1 = ((P4[g1] + P4[PROWS + g1]) + P4[2 * PROWS + g1])
                   + P4[3 * PROWS + g1];
    out_scores[t] = wslot[2 * t] * s0 + wslot[2 * t + 1] * s1;
}

// ---------------------------------------------------------------------------
extern "C" void kernel_launch(void* const* d_in, const int* in_sizes, int n_in,
                              void* d_out, int out_size, void* d_ws, size_t ws_size,
                              hipStream_t stream)
{
    const float* x  = (const float*)d_in[0];
    const float* W1 = (const float*)d_in[1];
    const float* b1 = (const float*)d_in[2];
    const float* W2 = (const float*)d_in[3];
    const float* Wg = (const float*)d_in[4];
    const float* bg = (const float*)d_in[5];

    float* out        = (float*)d_out;
    float* out_scores = out;            // [B, 1]
    float* out_logits = out + B_TOK;    // [B, E]

    char* ws = (char*)d_ws;
    int*            counts = (int*)           (ws + OFF_COUNTS);
    int*            cbase  = (int*)           (ws + OFF_CBASE);
    int*            bucket = (int*)           (ws + OFF_BUCKET);
    float*          wslot  = (float*)         (ws + OFF_WSLOT);
    int*            route  = (int*)           (ws + OFF_ROUTE);
    int*            inv    = (int*)           (ws + OFF_INV);
    float*          WgT    = (float*)         (ws + OFF_WGT);
    float*          P4     = (float*)         (ws + OFF_P4);
    unsigned short* W1q    = (unsigned short*)(ws + OFF_W1Q);
    unsigned short* xb     = (unsigned short*)(ws + OFF_XB);

    hipMemsetAsync(counts, 0, NE * sizeof(int), stream);

    wg_transpose_kernel<<<1, 256, 0, stream>>>(Wg, WgT);

    prep_w1_kernel<<<NE * NKSTEP, 256, 0, stream>>>(W1, W1q);

    gate_logits_kernel<<<B_TOK / 64, 256, 0, stream>>>(x, WgT, bg, out_logits,
                                                       wslot, route, xb);

    route_kernel<<<B_TOK / 1024, 1024, 0, stream>>>(route, counts, bucket);

    prefix_kernel<<<1, 64, 0, stream>>>(counts, cbase);

    invfill_kernel<<<NE * (B_TOK / 256), 256, 0, stream>>>(bucket, counts,
                                                           cbase, inv);

    expert_mfma_kernel<<<NE * 4 * PTMAX, 256, 0, stream>>>(
        xb, W1q, b1, W2, counts, cbase, bucket, P4);

    combine_kernel<<<B_TOK / 256, 256, 0, stream>>>(inv, P4, wslot, out_scores);
}